// Round 7
// baseline (1681.767 us; speedup 1.0000x reference)
//
#include <hip/hip_runtime.h>

#define ALPHA_F 0.1f
#define DEPTH 10
#define FEATS 512
#define CLS 32

__device__ __forceinline__ unsigned bf16rne(float f) {
  unsigned u = __float_as_uint(f);
  return (u + 0x7fffu + ((u >> 16) & 1u)) >> 16;   // round-to-nearest-even bf16
}
__device__ __forceinline__ float blo(unsigned q) { return __uint_as_float(q << 16); }
__device__ __forceinline__ float bhi(unsigned q) { return __uint_as_float(q & 0xffff0000u); }

// ---------------- degree count + per-edge rank ----------------
__global__ __launch_bounds__(256) void k_deg(const int* __restrict__ dst, int E, int N,
                                             unsigned* __restrict__ deg,
                                             unsigned* __restrict__ rank) {
  int i = blockIdx.x * 256 + threadIdx.x;
  if (i >= E) return;
  int d = dst[i];
  unsigned r = 0;
  if ((unsigned)d < (unsigned)N) r = atomicAdd(&deg[d], 1u);
  rank[i] = r;
}

// ---------------- generic exclusive scan (single block, 1024 threads) ----------------
__global__ __launch_bounds__(1024) void k_scan(const unsigned* __restrict__ in, int N,
                                               unsigned* __restrict__ out) {
  __shared__ unsigned sums[1024];
  int t = threadIdx.x;
  int chunk = (N + 1023) >> 10;
  int beg = t * chunk;
  int end = min(beg + chunk, N);
  unsigned s = 0;
  for (int i = beg; i < end; ++i) s += in[i];
  sums[t] = s;
  __syncthreads();
  for (int off = 1; off < 1024; off <<= 1) {
    unsigned v = (t >= off) ? sums[t - off] : 0u;
    __syncthreads();
    sums[t] += v;
    __syncthreads();
  }
  unsigned pre = (t == 0) ? 0u : sums[t - 1];
  for (int i = beg; i < end; ++i) { out[i] = pre; pre += in[i]; }
  if (t == 1023) out[N] = pre;
}

// ---------------- degree histogram (bins 0..256) ----------------
__global__ __launch_bounds__(256) void k_hist(const unsigned* __restrict__ deg, int N,
                                              unsigned* __restrict__ hist) {
  int i = blockIdx.x * 256 + threadIdx.x;
  if (i >= N) return;
  atomicAdd(&hist[min(deg[i], 256u)], 1u);
}

// ---------------- counting-sort scatter: perm, inv, be ----------------
__global__ __launch_bounds__(256) void k_perm(const unsigned* __restrict__ deg,
                                              const unsigned* __restrict__ rowst,
                                              unsigned* __restrict__ binoff2, int N,
                                              unsigned* __restrict__ perm,
                                              unsigned* __restrict__ inv,
                                              uint2* __restrict__ be) {
  int i = blockIdx.x * 256 + threadIdx.x;
  if (i >= N) return;
  unsigned d = deg[i];
  unsigned b = min(d, 256u);
  unsigned pos = atomicAdd(&binoff2[b], 1u);
  perm[pos] = (unsigned)i;
  inv[i] = pos;
  unsigned r0 = rowst[i];
  be[pos] = make_uint2(r0, r0 + d);
}

// ---------------- CSR fill into sorted src-space: col2[slot] = inv[src] ----------------
__global__ __launch_bounds__(256) void k_fill(const int* __restrict__ src,
                                              const int* __restrict__ dst,
                                              const unsigned* __restrict__ rank,
                                              const unsigned* __restrict__ rowst,
                                              const unsigned* __restrict__ inv,
                                              int E, int N,
                                              unsigned* __restrict__ col2) {
  int e = blockIdx.x * 256 + threadIdx.x;
  if (e >= E) return;
  int s = src[e];
  int d = dst[e];
  if ((unsigned)s >= (unsigned)N || (unsigned)d >= (unsigned)N) return;  // safety guard
  col2[rowst[d] + rank[e]] = inv[s];
}

// ---------------- fused MLP (round-5 structure): outputs in SORTED space ----------
// h0s[inv[row]], u0[inv[row]] = bf16(rs*h0), rss[inv[row]] = rsqrt(max(deg,1)).
__global__ __launch_bounds__(256) void k_mlp(const float* __restrict__ x,
                                             const float* __restrict__ W1,
                                             const float* __restrict__ b1,
                                             const float* __restrict__ W2,
                                             const float* __restrict__ b2,
                                             const unsigned* __restrict__ deg,
                                             const unsigned* __restrict__ inv,
                                             float* __restrict__ h0s,
                                             unsigned short* __restrict__ u0,
                                             float* __restrict__ rss, int N) {
  __shared__ float XHs[64 * 65];   // Xs (stride 64) during GEMM1, Hs (stride 65) after
  __shared__ float W2s[64 * 32];
  __shared__ float b1s[64];
  __shared__ float b2s[32];
  int t = threadIdx.x;
  int m0 = blockIdx.x * 64;

  for (int i = t; i < 64 * 32; i += 256) W2s[i] = W2[i];
  if (t < 64) b1s[t] = b1[t];
  if (t < 32) b2s[t] = b2[t];

  int c = t & 31;   // col pair base (c, c+32)
  int h = t >> 5;   // row group 0..7 -> rows h*8+i
  float acc[8][2];
#pragma unroll
  for (int i = 0; i < 8; ++i) { acc[i][0] = 0.f; acc[i][1] = 0.f; }

  for (int k0 = 0; k0 < FEATS; k0 += 64) {
    __syncthreads();
    // stage X tile [64 rows][64 k]: 512 float4 over 256 threads
#pragma unroll
    for (int j = 0; j < 2; ++j) {
      int F = j * 256 + t;          // float4-pair index
      int r = F >> 3, q = F & 7;
      int row = m0 + r;
      float4 v = make_float4(0.f, 0.f, 0.f, 0.f);
      if (row < N) v = *(const float4*)(x + (size_t)row * FEATS + k0 + q * 8);
      *(float4*)(XHs + r * 64 + q * 8) = v;
      float4 v2 = make_float4(0.f, 0.f, 0.f, 0.f);
      if (row < N) v2 = *(const float4*)(x + (size_t)row * FEATS + k0 + q * 8 + 4);
      *(float4*)(XHs + r * 64 + q * 8 + 4) = v2;
    }
    __syncthreads();
    const float* W1p = W1 + (size_t)k0 * 64;
#pragma unroll
    for (int k4 = 0; k4 < 16; ++k4) {
      int k = k4 * 4;
      float4 xv[8];
#pragma unroll
      for (int i = 0; i < 8; ++i) xv[i] = *(const float4*)(XHs + (h * 8 + i) * 64 + k);
#pragma unroll
      for (int j = 0; j < 4; ++j) {
        float w0 = W1p[(k + j) * 64 + c];        // L2-resident, dedup'd across waves
        float w1 = W1p[(k + j) * 64 + c + 32];
#pragma unroll
        for (int i = 0; i < 8; ++i) {
          float xx = ((const float*)&xv[i])[j];
          acc[i][0] += xx * w0;
          acc[i][1] += xx * w1;
        }
      }
    }
  }
  __syncthreads();
  // bias + relu -> Hs (stride 65)
#pragma unroll
  for (int i = 0; i < 8; ++i) {
    int r = h * 8 + i;
    float v0 = acc[i][0] + b1s[c];
    float v1 = acc[i][1] + b1s[c + 32];
    XHs[r * 65 + c] = v0 > 0.f ? v0 : 0.f;
    XHs[r * 65 + c + 32] = v1 > 0.f ? v1 : 0.f;
  }
  __syncthreads();
  // layer 2: thread -> class cc = t&31, rows h*8+i; scatter to sorted space
  int cc = t & 31;
#pragma unroll
  for (int i = 0; i < 8; ++i) {
    int r = h * 8 + i;
    float s = b2s[cc];
#pragma unroll
    for (int k = 0; k < 64; ++k) s += XHs[r * 65 + k] * W2s[k * 32 + cc];
    int row = m0 + r;
    if (row < N) {
      unsigned g = inv[row];
      float dv = (float)deg[row];
      float rsv = rsqrtf(fmaxf(dv, 1.0f));
      h0s[(size_t)g * CLS + cc] = s;
      u0[(size_t)g * CLS + cc] = (unsigned short)bf16rne(rsv * s);
      if (cc == 0) rss[g] = rsv;
    }
  }
}

// ---------------- one APPNP step, fully in sorted space ----------------
// non-last: u_out[g] = bf16( 0.1*rss[g]*h0s[g] + 0.9*rss[g]^2 * sum_e u_in[col2[e]] )
// last:     out[perm[g]] = 0.1*h0s[g] + 0.9*rss[g] * sum_e u_in[col2[e]]   (f32)
// 4 lanes per node; u row = 4 uint4 (32 bf16, 64 B); lane owns one uint4 (8 classes).
template <bool LAST>
__global__ __launch_bounds__(256) void k_prop(const unsigned* __restrict__ u_in,
                                              const float* __restrict__ h0s,
                                              const float* __restrict__ rss,
                                              const uint2* __restrict__ be,
                                              const unsigned* __restrict__ col2,
                                              const unsigned* __restrict__ perm,
                                              void* __restrict__ out, int N) {
  int t = blockIdx.x * 256 + threadIdx.x;
  int g = t >> 2;
  if (g >= N) return;
  int l = t & 3;   // lane's uint4 (classes l*8 .. l*8+7)
  uint2 brange = be[g];
  unsigned beg = brange.x, end = brange.y;
  const uint4* up = (const uint4*)u_in + l;
  float a[8], b[8];
#pragma unroll
  for (int j = 0; j < 8; ++j) { a[j] = 0.f; b[j] = 0.f; }
  unsigned e = beg;
  for (; e + 8 <= end; e += 8) {
    unsigned s0 = col2[e + 0], s1 = col2[e + 1], s2 = col2[e + 2], s3 = col2[e + 3];
    unsigned s4 = col2[e + 4], s5 = col2[e + 5], s6 = col2[e + 6], s7 = col2[e + 7];
    uint4 q0 = up[(size_t)s0 * 4];
    uint4 q1 = up[(size_t)s1 * 4];
    uint4 q2 = up[(size_t)s2 * 4];
    uint4 q3 = up[(size_t)s3 * 4];
    uint4 q4 = up[(size_t)s4 * 4];
    uint4 q5 = up[(size_t)s5 * 4];
    uint4 q6 = up[(size_t)s6 * 4];
    uint4 q7 = up[(size_t)s7 * 4];
    a[0] += blo(q0.x); a[1] += bhi(q0.x); a[2] += blo(q0.y); a[3] += bhi(q0.y);
    a[4] += blo(q0.z); a[5] += bhi(q0.z); a[6] += blo(q0.w); a[7] += bhi(q0.w);
    b[0] += blo(q1.x); b[1] += bhi(q1.x); b[2] += blo(q1.y); b[3] += bhi(q1.y);
    b[4] += blo(q1.z); b[5] += bhi(q1.z); b[6] += blo(q1.w); b[7] += bhi(q1.w);
    a[0] += blo(q2.x); a[1] += bhi(q2.x); a[2] += blo(q2.y); a[3] += bhi(q2.y);
    a[4] += blo(q2.z); a[5] += bhi(q2.z); a[6] += blo(q2.w); a[7] += bhi(q2.w);
    b[0] += blo(q3.x); b[1] += bhi(q3.x); b[2] += blo(q3.y); b[3] += bhi(q3.y);
    b[4] += blo(q3.z); b[5] += bhi(q3.z); b[6] += blo(q3.w); b[7] += bhi(q3.w);
    a[0] += blo(q4.x); a[1] += bhi(q4.x); a[2] += blo(q4.y); a[3] += bhi(q4.y);
    a[4] += blo(q4.z); a[5] += bhi(q4.z); a[6] += blo(q4.w); a[7] += bhi(q4.w);
    b[0] += blo(q5.x); b[1] += bhi(q5.x); b[2] += blo(q5.y); b[3] += bhi(q5.y);
    b[4] += blo(q5.z); b[5] += bhi(q5.z); b[6] += blo(q5.w); b[7] += bhi(q5.w);
    a[0] += blo(q6.x); a[1] += bhi(q6.x); a[2] += blo(q6.y); a[3] += bhi(q6.y);
    a[4] += blo(q6.z); a[5] += bhi(q6.z); a[6] += blo(q6.w); a[7] += bhi(q6.w);
    b[0] += blo(q7.x); b[1] += bhi(q7.x); b[2] += blo(q7.y); b[3] += bhi(q7.y);
    b[4] += blo(q7.z); b[5] += bhi(q7.z); b[6] += blo(q7.w); b[7] += bhi(q7.w);
  }
  for (; e < end; ++e) {
    unsigned s = col2[e];
    uint4 q = up[(size_t)s * 4];
    a[0] += blo(q.x); a[1] += bhi(q.x); a[2] += blo(q.y); a[3] += bhi(q.y);
    a[4] += blo(q.z); a[5] += bhi(q.z); a[6] += blo(q.w); a[7] += bhi(q.w);
  }
#pragma unroll
  for (int j = 0; j < 8; ++j) a[j] += b[j];
  float rsv = rss[g];
  const float* h0p = h0s + (size_t)g * CLS + l * 8;
  float4 h0a = *(const float4*)(h0p);
  float4 h0b = *(const float4*)(h0p + 4);
  if (LAST) {
    float ca = ALPHA_F, cb = (1.0f - ALPHA_F) * rsv;
    unsigned node = perm[g];
    float* op = (float*)out + (size_t)node * CLS + l * 8;
    *(float4*)(op) = make_float4(ca * h0a.x + cb * a[0], ca * h0a.y + cb * a[1],
                                 ca * h0a.z + cb * a[2], ca * h0a.w + cb * a[3]);
    *(float4*)(op + 4) = make_float4(ca * h0b.x + cb * a[4], ca * h0b.y + cb * a[5],
                                     ca * h0b.z + cb * a[6], ca * h0b.w + cb * a[7]);
  } else {
    float ca = ALPHA_F * rsv, cb = (1.0f - ALPHA_F) * rsv * rsv;
    float o0 = ca * h0a.x + cb * a[0], o1 = ca * h0a.y + cb * a[1];
    float o2 = ca * h0a.z + cb * a[2], o3 = ca * h0a.w + cb * a[3];
    float o4 = ca * h0b.x + cb * a[4], o5 = ca * h0b.y + cb * a[5];
    float o6 = ca * h0b.z + cb * a[6], o7 = ca * h0b.w + cb * a[7];
    uint4 p;
    p.x = bf16rne(o0) | (bf16rne(o1) << 16);
    p.y = bf16rne(o2) | (bf16rne(o3) << 16);
    p.z = bf16rne(o4) | (bf16rne(o5) << 16);
    p.w = bf16rne(o6) | (bf16rne(o7) << 16);
    *((uint4*)out + (size_t)g * 4 + l) = p;
  }
}

extern "C" void kernel_launch(void* const* d_in, const int* in_sizes, int n_in,
                              void* d_out, int out_size, void* d_ws, size_t ws_size,
                              hipStream_t stream) {
  const float* x = (const float*)d_in[0];
  const int* edges = (const int*)d_in[1];   // harness stages integer inputs as int32
  const float* W1 = (const float*)d_in[2];
  const float* b1 = (const float*)d_in[3];
  const float* W2 = (const float*)d_in[4];
  const float* b2 = (const float*)d_in[5];
  int N = in_sizes[0] / FEATS;
  int E = in_sizes[1] / 2;
  const int* src = edges;
  const int* dst = edges + E;

  char* ws = (char*)d_ws;
  auto align64 = [](size_t v) { return (v + 63) & ~(size_t)63; };
  size_t o = 0;
  unsigned* deg = (unsigned*)(ws + o);     o = align64(o + (size_t)N * 4);
  unsigned* rowst = (unsigned*)(ws + o);   o = align64(o + (size_t)(N + 1) * 4);
  unsigned* hist = (unsigned*)(ws + o);    o = align64(o + 258 * 4);
  unsigned* binoff = (unsigned*)(ws + o);  o = align64(o + 258 * 4);
  unsigned* binoff2 = (unsigned*)(ws + o); o = align64(o + 258 * 4);
  unsigned* perm = (unsigned*)(ws + o);    o = align64(o + (size_t)N * 4);
  unsigned* inv = (unsigned*)(ws + o);     o = align64(o + (size_t)N * 4);
  float* rss = (float*)(ws + o);           o = align64(o + (size_t)N * 4);
  uint2* be = (uint2*)(ws + o);            o = align64(o + (size_t)N * 8);
  unsigned* rank = (unsigned*)(ws + o);    o = align64(o + (size_t)E * 4);
  unsigned* col2 = (unsigned*)(ws + o);    o = align64(o + (size_t)E * 4);
  float* h0s = (float*)(ws + o);           o = align64(o + (size_t)N * CLS * 4);
  unsigned* uA = (unsigned*)(ws + o);      o = align64(o + (size_t)N * CLS * 2);
  unsigned* uB = (unsigned*)(ws + o);      o = align64(o + (size_t)N * CLS * 2);
  // total ws use ~54.3 MB

  hipMemsetAsync(deg, 0, (size_t)N * 4, stream);
  hipMemsetAsync(hist, 0, 258 * 4, stream);
  k_deg<<<(E + 255) / 256, 256, 0, stream>>>(dst, E, N, deg, rank);
  k_scan<<<1, 1024, 0, stream>>>(deg, N, rowst);
  k_hist<<<(N + 255) / 256, 256, 0, stream>>>(deg, N, hist);
  k_scan<<<1, 1024, 0, stream>>>(hist, 257, binoff);
  hipMemcpyAsync(binoff2, binoff, 258 * 4, hipMemcpyDeviceToDevice, stream);
  k_perm<<<(N + 255) / 256, 256, 0, stream>>>(deg, rowst, binoff2, N, perm, inv, be);
  k_fill<<<(E + 255) / 256, 256, 0, stream>>>(src, dst, rank, rowst, inv, E, N, col2);
  k_mlp<<<(N + 63) / 64, 256, 0, stream>>>(x, W1, b1, W2, b2, deg, inv, h0s,
                                           (unsigned short*)uA, rss, N);

  float* outF = (float*)d_out;
  const unsigned* uin = uA;
  for (int it = 0; it < DEPTH - 1; ++it) {
    unsigned* uo = (it & 1) ? uA : uB;
    k_prop<false><<<((N * 4) + 255) / 256, 256, 0, stream>>>(uin, h0s, rss, be, col2,
                                                             perm, uo, N);
    uin = uo;
  }
  k_prop<true><<<((N * 4) + 255) / 256, 256, 0, stream>>>(uin, h0s, rss, be, col2,
                                                          perm, outF, N);
}

// Round 9
// 1119.795 us; speedup vs baseline: 1.5019x; 1.5019x over previous
//
#include <hip/hip_runtime.h>

#define ALPHA_F 0.1f
#define DEPTH 10
#define FEATS 512
#define CLS 32

__device__ __forceinline__ unsigned bf16rne(float f) {
  unsigned u = __float_as_uint(f);
  return (u + 0x7fffu + ((u >> 16) & 1u)) >> 16;   // round-to-nearest-even bf16
}
__device__ __forceinline__ float blo(unsigned q) { return __uint_as_float(q << 16); }
__device__ __forceinline__ float bhi(unsigned q) { return __uint_as_float(q & 0xffff0000u); }

// ---------------- degree count + per-edge rank ----------------
__global__ __launch_bounds__(256) void k_deg(const int* __restrict__ dst, int E, int N,
                                             unsigned* __restrict__ deg,
                                             unsigned* __restrict__ rank) {
  int i = blockIdx.x * 256 + threadIdx.x;
  if (i >= E) return;
  int d = dst[i];
  unsigned r = 0;
  if ((unsigned)d < (unsigned)N) r = atomicAdd(&deg[d], 1u);
  rank[i] = r;
}

// ---------------- padded exclusive scan: rowst2 = scan(roundup16(deg)) ----------------
__global__ __launch_bounds__(1024) void k_scanp(const unsigned* __restrict__ deg, int N,
                                                unsigned* __restrict__ rowst2) {
  __shared__ unsigned sums[1024];
  int t = threadIdx.x;
  int chunk = (N + 1023) >> 10;
  int beg = t * chunk;
  int end = min(beg + chunk, N);
  unsigned s = 0;
  for (int i = beg; i < end; ++i) s += (deg[i] + 15u) & ~15u;
  sums[t] = s;
  __syncthreads();
  for (int off = 1; off < 1024; off <<= 1) {
    unsigned v = (t >= off) ? sums[t - off] : 0u;
    __syncthreads();
    sums[t] += v;
    __syncthreads();
  }
  unsigned pre = (t == 0) ? 0u : sums[t - 1];
  for (int i = beg; i < end; ++i) { rowst2[i] = pre; pre += (deg[i] + 15u) & ~15u; }
  if (t == 1023) rowst2[N] = pre;
}

// ---------------- init col2 to N (padding slots gather the zero row) ----------------
__global__ __launch_bounds__(256) void k_colinit(unsigned* __restrict__ col2, int cap, int N) {
  int i = blockIdx.x * 256 + threadIdx.x;
  if (i < cap) col2[i] = (unsigned)N;
}

// ---------------- CSR fill, atomic-free: col2[rowst2[d]+rank[e]] = src[e] ----------------
__global__ __launch_bounds__(256) void k_fill(const int* __restrict__ src,
                                              const int* __restrict__ dst,
                                              const unsigned* __restrict__ rank,
                                              const unsigned* __restrict__ rowst2,
                                              int E, int N,
                                              unsigned* __restrict__ col2) {
  int e = blockIdx.x * 256 + threadIdx.x;
  if (e >= E) return;
  int s = src[e];
  int d = dst[e];
  if ((unsigned)s >= (unsigned)N || (unsigned)d >= (unsigned)N) return;  // safety guard
  col2[rowst2[d] + rank[e]] = (unsigned)s;
}

// ---------------- fused MLP (round-5 structure): h0b bf16, u0 bf16, rs f32 ----------
__global__ __launch_bounds__(256) void k_mlp(const float* __restrict__ x,
                                             const float* __restrict__ W1,
                                             const float* __restrict__ b1,
                                             const float* __restrict__ W2,
                                             const float* __restrict__ b2,
                                             const unsigned* __restrict__ deg,
                                             unsigned short* __restrict__ h0b,
                                             unsigned short* __restrict__ u0,
                                             float* __restrict__ rs, int N) {
  __shared__ float XHs[64 * 65];   // Xs (stride 64) during GEMM1, Hs (stride 65) after
  __shared__ float W2s[64 * 32];
  __shared__ float b1s[64];
  __shared__ float b2s[32];
  int t = threadIdx.x;
  int m0 = blockIdx.x * 64;

  for (int i = t; i < 64 * 32; i += 256) W2s[i] = W2[i];
  if (t < 64) b1s[t] = b1[t];
  if (t < 32) b2s[t] = b2[t];

  int c = t & 31;   // col pair base (c, c+32)
  int h = t >> 5;   // row group 0..7 -> rows h*8+i
  float acc[8][2];
#pragma unroll
  for (int i = 0; i < 8; ++i) { acc[i][0] = 0.f; acc[i][1] = 0.f; }

  for (int k0 = 0; k0 < FEATS; k0 += 64) {
    __syncthreads();
#pragma unroll
    for (int j = 0; j < 2; ++j) {
      int F = j * 256 + t;
      int r = F >> 3, q = F & 7;
      int row = m0 + r;
      float4 v = make_float4(0.f, 0.f, 0.f, 0.f);
      if (row < N) v = *(const float4*)(x + (size_t)row * FEATS + k0 + q * 8);
      *(float4*)(XHs + r * 64 + q * 8) = v;
      float4 v2 = make_float4(0.f, 0.f, 0.f, 0.f);
      if (row < N) v2 = *(const float4*)(x + (size_t)row * FEATS + k0 + q * 8 + 4);
      *(float4*)(XHs + r * 64 + q * 8 + 4) = v2;
    }
    __syncthreads();
    const float* W1p = W1 + (size_t)k0 * 64;
#pragma unroll
    for (int k4 = 0; k4 < 16; ++k4) {
      int k = k4 * 4;
      float4 xv[8];
#pragma unroll
      for (int i = 0; i < 8; ++i) xv[i] = *(const float4*)(XHs + (h * 8 + i) * 64 + k);
#pragma unroll
      for (int j = 0; j < 4; ++j) {
        float w0 = W1p[(k + j) * 64 + c];        // L2-resident, dedup'd across waves
        float w1 = W1p[(k + j) * 64 + c + 32];
#pragma unroll
        for (int i = 0; i < 8; ++i) {
          float xx = ((const float*)&xv[i])[j];
          acc[i][0] += xx * w0;
          acc[i][1] += xx * w1;
        }
      }
    }
  }
  __syncthreads();
#pragma unroll
  for (int i = 0; i < 8; ++i) {
    int r = h * 8 + i;
    float v0 = acc[i][0] + b1s[c];
    float v1 = acc[i][1] + b1s[c + 32];
    XHs[r * 65 + c] = v0 > 0.f ? v0 : 0.f;
    XHs[r * 65 + c + 32] = v1 > 0.f ? v1 : 0.f;
  }
  __syncthreads();
  int cc = t & 31;
#pragma unroll
  for (int i = 0; i < 8; ++i) {
    int r = h * 8 + i;
    float s = b2s[cc];
#pragma unroll
    for (int k = 0; k < 64; ++k) s += XHs[r * 65 + k] * W2s[k * 32 + cc];
    int row = m0 + r;
    if (row < N) {
      float dv = (float)deg[row];
      float rsv = rsqrtf(fmaxf(dv, 1.0f));
      h0b[(size_t)row * CLS + cc] = (unsigned short)bf16rne(s);
      u0[(size_t)row * CLS + cc] = (unsigned short)bf16rne(rsv * s);
      if (cc == 0) rs[row] = rsv;
    }
  }
}

// ---------------- one APPNP step on bf16 scaled state ----------------
// Rows padded to x16 with dummy src N (u row N == 0). 4 lanes/node, lane owns uint4.
// 16-deep gather batches, uint4 col loads (row starts 16-aligned).
template <bool LAST>
__global__ __launch_bounds__(256) void k_prop(const unsigned* __restrict__ u_in,
                                              const unsigned short* __restrict__ h0b,
                                              const float* __restrict__ rs,
                                              const unsigned* __restrict__ rowst2,
                                              const unsigned* __restrict__ col2,
                                              void* __restrict__ out, int N) {
  int t = blockIdx.x * 256 + threadIdx.x;
  int g = t >> 2;
  if (g >= N) return;
  int l = t & 3;   // lane's uint4 (classes l*8 .. l*8+7)
  unsigned beg = rowst2[g];
  unsigned end = rowst2[g + 1];
  const uint4* up = (const uint4*)u_in + l;
  const uint4* colv = (const uint4*)col2;
  float a[8];
#pragma unroll
  for (int j = 0; j < 8; ++j) a[j] = 0.f;
  for (unsigned e = beg; e < end; e += 16) {
    unsigned e4 = e >> 2;
    uint4 c0 = colv[e4 + 0];
    uint4 c1 = colv[e4 + 1];
    uint4 c2 = colv[e4 + 2];
    uint4 c3 = colv[e4 + 3];
    uint4 q0 = up[(size_t)c0.x * 4];
    uint4 q1 = up[(size_t)c0.y * 4];
    uint4 q2 = up[(size_t)c0.z * 4];
    uint4 q3 = up[(size_t)c0.w * 4];
    uint4 q4 = up[(size_t)c1.x * 4];
    uint4 q5 = up[(size_t)c1.y * 4];
    uint4 q6 = up[(size_t)c1.z * 4];
    uint4 q7 = up[(size_t)c1.w * 4];
    uint4 q8 = up[(size_t)c2.x * 4];
    uint4 q9 = up[(size_t)c2.y * 4];
    uint4 qa = up[(size_t)c2.z * 4];
    uint4 qb = up[(size_t)c2.w * 4];
    uint4 qc = up[(size_t)c3.x * 4];
    uint4 qd = up[(size_t)c3.y * 4];
    uint4 qe = up[(size_t)c3.z * 4];
    uint4 qf = up[(size_t)c3.w * 4];
#define ACC(q) \
    a[0] += blo(q.x); a[1] += bhi(q.x); a[2] += blo(q.y); a[3] += bhi(q.y); \
    a[4] += blo(q.z); a[5] += bhi(q.z); a[6] += blo(q.w); a[7] += bhi(q.w);
    ACC(q0) ACC(q1) ACC(q2) ACC(q3) ACC(q4) ACC(q5) ACC(q6) ACC(q7)
    ACC(q8) ACC(q9) ACC(qa) ACC(qb) ACC(qc) ACC(qd) ACC(qe) ACC(qf)
#undef ACC
  }
  float rsv = rs[g];
  uint4 hq = *((const uint4*)h0b + (size_t)g * 4 + l);
  float h0v[8] = { blo(hq.x), bhi(hq.x), blo(hq.y), bhi(hq.y),
                   blo(hq.z), bhi(hq.z), blo(hq.w), bhi(hq.w) };
  if (LAST) {
    float ca = ALPHA_F, cb = (1.0f - ALPHA_F) * rsv;
    float* op = (float*)out + (size_t)g * CLS + l * 8;
    *(float4*)(op) = make_float4(ca * h0v[0] + cb * a[0], ca * h0v[1] + cb * a[1],
                                 ca * h0v[2] + cb * a[2], ca * h0v[3] + cb * a[3]);
    *(float4*)(op + 4) = make_float4(ca * h0v[4] + cb * a[4], ca * h0v[5] + cb * a[5],
                                     ca * h0v[6] + cb * a[6], ca * h0v[7] + cb * a[7]);
  } else {
    float ca = ALPHA_F * rsv, cb = (1.0f - ALPHA_F) * rsv * rsv;
    float o[8];
#pragma unroll
    for (int j = 0; j < 8; ++j) o[j] = ca * h0v[j] + cb * a[j];
    uint4 p;
    p.x = bf16rne(o[0]) | (bf16rne(o[1]) << 16);
    p.y = bf16rne(o[2]) | (bf16rne(o[3]) << 16);
    p.z = bf16rne(o[4]) | (bf16rne(o[5]) << 16);
    p.w = bf16rne(o[6]) | (bf16rne(o[7]) << 16);
    *((uint4*)out + (size_t)g * 4 + l) = p;
  }
}

extern "C" void kernel_launch(void* const* d_in, const int* in_sizes, int n_in,
                              void* d_out, int out_size, void* d_ws, size_t ws_size,
                              hipStream_t stream) {
  const float* x = (const float*)d_in[0];
  const int* edges = (const int*)d_in[1];   // harness stages integer inputs as int32
  const float* W1 = (const float*)d_in[2];
  const float* b1 = (const float*)d_in[3];
  const float* W2 = (const float*)d_in[4];
  const float* b2 = (const float*)d_in[5];
  int N = in_sizes[0] / FEATS;
  int E = in_sizes[1] / 2;
  const int* src = edges;
  const int* dst = edges + E;
  int cap = E + 16 * N;           // upper bound on padded edge count

  char* ws = (char*)d_ws;
  auto align64 = [](size_t v) { return (v + 63) & ~(size_t)63; };
  size_t o = 0;
  unsigned* deg = (unsigned*)(ws + o);    o = align64(o + (size_t)N * 4);
  unsigned* rowst2 = (unsigned*)(ws + o); o = align64(o + (size_t)(N + 1) * 4);
  float* rs = (float*)(ws + o);           o = align64(o + (size_t)N * 4);
  unsigned* rank = (unsigned*)(ws + o);   o = align64(o + (size_t)E * 4);
  unsigned* col2 = (unsigned*)(ws + o);   o = align64(o + (size_t)cap * 4);
  unsigned short* h0b = (unsigned short*)(ws + o); o = align64(o + (size_t)N * CLS * 2);
  unsigned* uA = (unsigned*)(ws + o);     o = align64(o + (size_t)(N + 1) * CLS * 2);
  unsigned* uB = (unsigned*)(ws + o);     o = align64(o + (size_t)(N + 1) * CLS * 2);
  // total ws use ~53 MB

  hipMemsetAsync(deg, 0, (size_t)N * 4, stream);
  hipMemsetAsync(uA + (size_t)N * 16, 0, 64, stream);   // zero row N (dummy gather target)
  hipMemsetAsync(uB + (size_t)N * 16, 0, 64, stream);
  k_deg<<<(E + 255) / 256, 256, 0, stream>>>(dst, E, N, deg, rank);
  k_scanp<<<1, 1024, 0, stream>>>(deg, N, rowst2);
  k_colinit<<<(cap + 255) / 256, 256, 0, stream>>>(col2, cap, N);
  k_fill<<<(E + 255) / 256, 256, 0, stream>>>(src, dst, rank, rowst2, E, N, col2);
  k_mlp<<<(N + 63) / 64, 256, 0, stream>>>(x, W1, b1, W2, b2, deg, h0b,
                                           (unsigned short*)uA, rs, N);

  float* outF = (float*)d_out;
  const unsigned* uin = uA;
  for (int it = 0; it < DEPTH - 1; ++it) {
    unsigned* uo = (it & 1) ? uA : uB;
    k_prop<false><<<((N * 4) + 255) / 256, 256, 0, stream>>>(uin, h0b, rs, rowst2, col2,
                                                             uo, N);
    uin = uo;
  }
  k_prop<true><<<((N * 4) + 255) / 256, 256, 0, stream>>>(uin, h0b, rs, rowst2, col2,
                                                          outF, N);
}

// Round 10
// 1067.861 us; speedup vs baseline: 1.5749x; 1.0486x over previous
//
#include <hip/hip_runtime.h>
#include <hip/hip_fp16.h>

#define ALPHA_F 0.1f
#define DEPTH 10
#define FEATS 512
#define CLS 32

typedef __attribute__((ext_vector_type(8))) short short8v;
typedef __attribute__((ext_vector_type(4))) short short4v;
typedef __attribute__((ext_vector_type(4))) float f32x4;

__device__ __forceinline__ unsigned bf16rne(float f) {
  unsigned u = __float_as_uint(f);
  return (u + 0x7fffu + ((u >> 16) & 1u)) >> 16;   // round-to-nearest-even bf16
}
__device__ __forceinline__ float f16l(unsigned q) {
  __half_raw r; r.x = (unsigned short)(q & 0xffffu);
  return __half2float(*reinterpret_cast<const __half*>(&r));
}
__device__ __forceinline__ float f16h(unsigned q) { return f16l(q >> 16); }
__device__ __forceinline__ unsigned f16pk(float a, float b) {
  __half2 h = __floats2half2_rn(a, b);          // x = a (low), y = b (high)
  return *reinterpret_cast<unsigned*>(&h);
}
__device__ __forceinline__ unsigned short f16u(float a) {
  __half h = __float2half_rn(a);
  return *reinterpret_cast<unsigned short*>(&h);
}

// ---------------- degree count + per-edge rank ----------------
__global__ __launch_bounds__(256) void k_deg(const int* __restrict__ dst, int E, int N,
                                             unsigned* __restrict__ deg,
                                             unsigned* __restrict__ rank) {
  int i = blockIdx.x * 256 + threadIdx.x;
  if (i >= E) return;
  int d = dst[i];
  unsigned r = 0;
  if ((unsigned)d < (unsigned)N) r = atomicAdd(&deg[d], 1u);
  rank[i] = r;
}

// ---------------- padded exclusive scan: rowst2 = scan(roundup16(deg)) ----------------
__global__ __launch_bounds__(1024) void k_scanp(const unsigned* __restrict__ deg, int N,
                                                unsigned* __restrict__ rowst2) {
  __shared__ unsigned sums[1024];
  int t = threadIdx.x;
  int chunk = (N + 1023) >> 10;
  int beg = t * chunk;
  int end = min(beg + chunk, N);
  unsigned s = 0;
  for (int i = beg; i < end; ++i) s += (deg[i] + 15u) & ~15u;
  sums[t] = s;
  __syncthreads();
  for (int off = 1; off < 1024; off <<= 1) {
    unsigned v = (t >= off) ? sums[t - off] : 0u;
    __syncthreads();
    sums[t] += v;
    __syncthreads();
  }
  unsigned pre = (t == 0) ? 0u : sums[t - 1];
  for (int i = beg; i < end; ++i) { rowst2[i] = pre; pre += (deg[i] + 15u) & ~15u; }
  if (t == 1023) rowst2[N] = pre;
}

// ---------------- init col2 to N (padding slots gather the zero row) ----------------
__global__ __launch_bounds__(256) void k_colinit(unsigned* __restrict__ col2, int cap, int N) {
  int i = blockIdx.x * 256 + threadIdx.x;
  if (i < cap) col2[i] = (unsigned)N;
}

// ---------------- CSR fill, atomic-free ----------------
__global__ __launch_bounds__(256) void k_fill(const int* __restrict__ src,
                                              const int* __restrict__ dst,
                                              const unsigned* __restrict__ rank,
                                              const unsigned* __restrict__ rowst2,
                                              int E, int N,
                                              unsigned* __restrict__ col2) {
  int e = blockIdx.x * 256 + threadIdx.x;
  if (e >= E) return;
  int s = src[e];
  int d = dst[e];
  if ((unsigned)s >= (unsigned)N || (unsigned)d >= (unsigned)N) return;  // safety guard
  col2[rowst2[d] + rank[e]] = (unsigned)s;
}

// ---------------- fused MLP: GEMM1 via MFMA bf16x3 (fp32-grade), GEMM2 fp32 VALU ------
// Block: 256 thr = 4 waves; tile 64 rows x 64 cols; K staged 32 at a time.
// LDS: A(hi/lo)[64][36] bf16, B^T(hi/lo)[64c][36k] bf16 (stride 36 -> conflict-free b64).
__global__ __launch_bounds__(256) void k_mlp(const float* __restrict__ x,
                                             const float* __restrict__ W1,
                                             const float* __restrict__ b1,
                                             const float* __restrict__ W2,
                                             const float* __restrict__ b2,
                                             const unsigned* __restrict__ deg,
                                             unsigned short* __restrict__ h0h,
                                             unsigned short* __restrict__ u0,
                                             float* __restrict__ rs, int N) {
  __shared__ __align__(16) unsigned char SB[18432];
  __shared__ float W2s[64 * 32];
  __shared__ float b1s[64];
  __shared__ float b2s[32];
  unsigned short* Ahi = (unsigned short*)SB;            // [64][36]
  unsigned short* Alo = (unsigned short*)(SB + 4608);
  unsigned short* Bhi = (unsigned short*)(SB + 9216);   // [64c][36k]
  unsigned short* Blo = (unsigned short*)(SB + 13824);
  float* Hs = (float*)SB;                               // [64][65] overlay after GEMM1

  int t = threadIdx.x;
  int m0 = blockIdx.x * 64;
  for (int i = t; i < 64 * 32; i += 256) W2s[i] = W2[i];
  if (t < 64) b1s[t] = b1[t];
  if (t < 32) b2s[t] = b2[t];

  int lane = t & 63, w = t >> 6;
  int lr = lane & 15, kb = lane >> 4;
  f32x4 acc[4];
#pragma unroll
  for (int n = 0; n < 4; ++n) acc[n] = (f32x4){0.f, 0.f, 0.f, 0.f};

  int sr = t >> 2, sq = t & 3;          // X staging: row sr, k = sq*8..+7
  int wk = t >> 3, wc = (t & 7) * 8;    // W1 staging: k row wk, cols wc..wc+7

  for (int k0 = 0; k0 < FEATS; k0 += 32) {
    __syncthreads();
    // ---- stage X[64][32] as hi/lo bf16 ----
    {
      int row = m0 + sr;
      const float* gp = x + (size_t)row * FEATS + k0 + sq * 8;
      float4 v0 = make_float4(0.f, 0.f, 0.f, 0.f), v1 = v0;
      if (row < N) { v0 = *(const float4*)gp; v1 = *(const float4*)(gp + 4); }
      float f[8] = {v0.x, v0.y, v0.z, v0.w, v1.x, v1.y, v1.z, v1.w};
      unsigned short hh[8], ll[8];
#pragma unroll
      for (int j = 0; j < 8; ++j) {
        unsigned hb = bf16rne(f[j]);
        float fh = __uint_as_float(hb << 16);
        hh[j] = (unsigned short)hb;
        ll[j] = (unsigned short)bf16rne(f[j] - fh);
      }
      int base = sr * 36 + sq * 8;
      *(ushort4*)(Ahi + base)     = make_ushort4(hh[0], hh[1], hh[2], hh[3]);
      *(ushort4*)(Ahi + base + 4) = make_ushort4(hh[4], hh[5], hh[6], hh[7]);
      *(ushort4*)(Alo + base)     = make_ushort4(ll[0], ll[1], ll[2], ll[3]);
      *(ushort4*)(Alo + base + 4) = make_ushort4(ll[4], ll[5], ll[6], ll[7]);
    }
    // ---- stage W1^T[64c][32k] as hi/lo bf16 ----
    {
      const float* wp = W1 + (size_t)(k0 + wk) * 64 + wc;
      float4 a0 = *(const float4*)wp, a1 = *(const float4*)(wp + 4);
      float g[8] = {a0.x, a0.y, a0.z, a0.w, a1.x, a1.y, a1.z, a1.w};
#pragma unroll
      for (int j = 0; j < 8; ++j) {
        unsigned hb = bf16rne(g[j]);
        float fh = __uint_as_float(hb << 16);
        Bhi[(wc + j) * 36 + wk] = (unsigned short)hb;
        Blo[(wc + j) * 36 + wk] = (unsigned short)bf16rne(g[j] - fh);
      }
    }
    __syncthreads();
    // ---- MFMA: each wave computes 16-row strip x 64 cols (4 tiles), bf16x3 ----
    int abase = (w * 16 + lr) * 36 + kb * 8;
    short4v a0h = *(short4v*)(Ahi + abase);
    short4v a1h = *(short4v*)(Ahi + abase + 4);
    short4v a0l = *(short4v*)(Alo + abase);
    short4v a1l = *(short4v*)(Alo + abase + 4);
    short8v ahi = __builtin_shufflevector(a0h, a1h, 0, 1, 2, 3, 4, 5, 6, 7);
    short8v alo = __builtin_shufflevector(a0l, a1l, 0, 1, 2, 3, 4, 5, 6, 7);
#pragma unroll
    for (int n = 0; n < 4; ++n) {
      int bbase = (n * 16 + lr) * 36 + kb * 8;
      short4v b0h = *(short4v*)(Bhi + bbase);
      short4v b1h = *(short4v*)(Bhi + bbase + 4);
      short4v b0l = *(short4v*)(Blo + bbase);
      short4v b1l = *(short4v*)(Blo + bbase + 4);
      short8v bhi = __builtin_shufflevector(b0h, b1h, 0, 1, 2, 3, 4, 5, 6, 7);
      short8v blo = __builtin_shufflevector(b0l, b1l, 0, 1, 2, 3, 4, 5, 6, 7);
      acc[n] = __builtin_amdgcn_mfma_f32_16x16x32_bf16(ahi, bhi, acc[n], 0, 0, 0);
      acc[n] = __builtin_amdgcn_mfma_f32_16x16x32_bf16(ahi, blo, acc[n], 0, 0, 0);
      acc[n] = __builtin_amdgcn_mfma_f32_16x16x32_bf16(alo, bhi, acc[n], 0, 0, 0);
    }
  }
  __syncthreads();
  // ---- bias + relu -> Hs[64][65] (C/D: col = lane&15, row = kb*4 + reg) ----
#pragma unroll
  for (int n = 0; n < 4; ++n) {
    int col = n * 16 + lr;
    float bv = b1s[col];
#pragma unroll
    for (int j = 0; j < 4; ++j) {
      int row = w * 16 + kb * 4 + j;
      float v = acc[n][j] + bv;
      Hs[row * 65 + col] = v > 0.f ? v : 0.f;
    }
  }
  __syncthreads();
  // ---- GEMM2 fp32: class cc = t&31, rows hgrp*8+i ----
  int cc = t & 31, hgrp = t >> 5;
#pragma unroll
  for (int i = 0; i < 8; ++i) {
    int r = hgrp * 8 + i;
    float s = b2s[cc];
#pragma unroll
    for (int k = 0; k < 64; ++k) s += Hs[r * 65 + k] * W2s[k * 32 + cc];
    int row = m0 + r;
    if (row < N) {
      float dv = (float)deg[row];
      float rsv = rsqrtf(fmaxf(dv, 1.0f));
      h0h[(size_t)row * CLS + cc] = f16u(s);
      u0[(size_t)row * CLS + cc] = f16u(rsv * s);
      if (cc == 0) rs[row] = rsv;
    }
  }
}

// ---------------- one APPNP step on fp16 scaled state ----------------
// Rows padded to x16 with dummy src N (u row N == 0). 4 lanes/node, lane owns uint4.
template <bool LAST>
__global__ __launch_bounds__(256) void k_prop(const unsigned* __restrict__ u_in,
                                              const unsigned short* __restrict__ h0h,
                                              const float* __restrict__ rs,
                                              const unsigned* __restrict__ rowst2,
                                              const unsigned* __restrict__ col2,
                                              void* __restrict__ out, int N) {
  int t = blockIdx.x * 256 + threadIdx.x;
  int g = t >> 2;
  if (g >= N) return;
  int l = t & 3;   // lane's uint4 (classes l*8 .. l*8+7)
  unsigned beg = rowst2[g];
  unsigned end = rowst2[g + 1];
  const uint4* up = (const uint4*)u_in + l;
  const uint4* colv = (const uint4*)col2;
  float a[8];
#pragma unroll
  for (int j = 0; j < 8; ++j) a[j] = 0.f;
  for (unsigned e = beg; e < end; e += 16) {
    unsigned e4 = e >> 2;
    uint4 c0 = colv[e4 + 0];
    uint4 c1 = colv[e4 + 1];
    uint4 c2 = colv[e4 + 2];
    uint4 c3 = colv[e4 + 3];
    uint4 q0 = up[(size_t)c0.x * 4];
    uint4 q1 = up[(size_t)c0.y * 4];
    uint4 q2 = up[(size_t)c0.z * 4];
    uint4 q3 = up[(size_t)c0.w * 4];
    uint4 q4 = up[(size_t)c1.x * 4];
    uint4 q5 = up[(size_t)c1.y * 4];
    uint4 q6 = up[(size_t)c1.z * 4];
    uint4 q7 = up[(size_t)c1.w * 4];
    uint4 q8 = up[(size_t)c2.x * 4];
    uint4 q9 = up[(size_t)c2.y * 4];
    uint4 qa = up[(size_t)c2.z * 4];
    uint4 qb = up[(size_t)c2.w * 4];
    uint4 qc = up[(size_t)c3.x * 4];
    uint4 qd = up[(size_t)c3.y * 4];
    uint4 qe = up[(size_t)c3.z * 4];
    uint4 qf = up[(size_t)c3.w * 4];
#define ACC(q) \
    a[0] += f16l(q.x); a[1] += f16h(q.x); a[2] += f16l(q.y); a[3] += f16h(q.y); \
    a[4] += f16l(q.z); a[5] += f16h(q.z); a[6] += f16l(q.w); a[7] += f16h(q.w);
    ACC(q0) ACC(q1) ACC(q2) ACC(q3) ACC(q4) ACC(q5) ACC(q6) ACC(q7)
    ACC(q8) ACC(q9) ACC(qa) ACC(qb) ACC(qc) ACC(qd) ACC(qe) ACC(qf)
#undef ACC
  }
  float rsv = rs[g];
  uint4 hq = *((const uint4*)h0h + (size_t)g * 4 + l);
  float h0v[8] = { f16l(hq.x), f16h(hq.x), f16l(hq.y), f16h(hq.y),
                   f16l(hq.z), f16h(hq.z), f16l(hq.w), f16h(hq.w) };
  if (LAST) {
    float ca = ALPHA_F, cb = (1.0f - ALPHA_F) * rsv;
    float* op = (float*)out + (size_t)g * CLS + l * 8;
    *(float4*)(op) = make_float4(ca * h0v[0] + cb * a[0], ca * h0v[1] + cb * a[1],
                                 ca * h0v[2] + cb * a[2], ca * h0v[3] + cb * a[3]);
    *(float4*)(op + 4) = make_float4(ca * h0v[4] + cb * a[4], ca * h0v[5] + cb * a[5],
                                     ca * h0v[6] + cb * a[6], ca * h0v[7] + cb * a[7]);
  } else {
    float ca = ALPHA_F * rsv, cb = (1.0f - ALPHA_F) * rsv * rsv;
    float o[8];
#pragma unroll
    for (int j = 0; j < 8; ++j) o[j] = ca * h0v[j] + cb * a[j];
    uint4 p;
    p.x = f16pk(o[0], o[1]);
    p.y = f16pk(o[2], o[3]);
    p.z = f16pk(o[4], o[5]);
    p.w = f16pk(o[6], o[7]);
    *((uint4*)out + (size_t)g * 4 + l) = p;
  }
}

extern "C" void kernel_launch(void* const* d_in, const int* in_sizes, int n_in,
                              void* d_out, int out_size, void* d_ws, size_t ws_size,
                              hipStream_t stream) {
  const float* x = (const float*)d_in[0];
  const int* edges = (const int*)d_in[1];   // harness stages integer inputs as int32
  const float* W1 = (const float*)d_in[2];
  const float* b1 = (const float*)d_in[3];
  const float* W2 = (const float*)d_in[4];
  const float* b2 = (const float*)d_in[5];
  int N = in_sizes[0] / FEATS;
  int E = in_sizes[1] / 2;
  const int* src = edges;
  const int* dst = edges + E;
  int cap = E + 16 * N;           // upper bound on padded edge count

  char* ws = (char*)d_ws;
  auto align64 = [](size_t v) { return (v + 63) & ~(size_t)63; };
  size_t o = 0;
  unsigned* deg = (unsigned*)(ws + o);    o = align64(o + (size_t)N * 4);
  unsigned* rowst2 = (unsigned*)(ws + o); o = align64(o + (size_t)(N + 1) * 4);
  float* rs = (float*)(ws + o);           o = align64(o + (size_t)N * 4);
  unsigned* rank = (unsigned*)(ws + o);   o = align64(o + (size_t)E * 4);
  unsigned* col2 = (unsigned*)(ws + o);   o = align64(o + (size_t)cap * 4);
  unsigned short* h0h = (unsigned short*)(ws + o); o = align64(o + (size_t)N * CLS * 2);
  unsigned* uA = (unsigned*)(ws + o);     o = align64(o + (size_t)(N + 1) * CLS * 2);
  unsigned* uB = (unsigned*)(ws + o);     o = align64(o + (size_t)(N + 1) * CLS * 2);
  // total ws use ~53 MB

  hipMemsetAsync(deg, 0, (size_t)N * 4, stream);
  hipMemsetAsync(uA + (size_t)N * 16, 0, 64, stream);   // zero row N (dummy gather target)
  hipMemsetAsync(uB + (size_t)N * 16, 0, 64, stream);
  k_deg<<<(E + 255) / 256, 256, 0, stream>>>(dst, E, N, deg, rank);
  k_scanp<<<1, 1024, 0, stream>>>(deg, N, rowst2);
  k_colinit<<<(cap + 255) / 256, 256, 0, stream>>>(col2, cap, N);
  k_fill<<<(E + 255) / 256, 256, 0, stream>>>(src, dst, rank, rowst2, E, N, col2);
  k_mlp<<<(N + 63) / 64, 256, 0, stream>>>(x, W1, b1, W2, b2, deg, h0h,
                                           (unsigned short*)uA, rs, N);

  float* outF = (float*)d_out;
  const unsigned* uin = uA;
  for (int it = 0; it < DEPTH - 1; ++it) {
    unsigned* uo = (it & 1) ? uA : uB;
    k_prop<false><<<((N * 4) + 255) / 256, 256, 0, stream>>>(uin, h0h, rs, rowst2, col2,
                                                             uo, N);
    uin = uo;
  }
  k_prop<true><<<((N * 4) + 255) / 256, 256, 0, stream>>>(uin, h0h, rs, rowst2, col2,
                                                          outF, N);
}